// Round 1
// baseline (739.627 us; speedup 1.0000x reference)
//
#include <hip/hip_runtime.h>

// Problem constants (match reference setup_inputs)
#define BB   4
#define LL   2048
#define CC   1024
#define NSEG 64
#define SEGLEN (LL / NSEG)   // 32
#define CBLK 256             // channels per block
#define CG   (CC / CBLK)     // 4 c-groups

// Complex scalar
struct Cplx { float r, i; };

__device__ __forceinline__ Cplx cmul(Cplx a, Cplx b) {
    Cplx o;
    o.r = fmaf(a.r, b.r, -a.i * b.i);
    o.i = fmaf(a.r, b.i,  a.i * b.r);
    return o;
}
// acc += a*b
__device__ __forceinline__ Cplx cfma(Cplx a, Cplx b, Cplx acc) {
    acc.r = fmaf(a.r, b.r, fmaf(-a.i, b.i, acc.r));
    acc.i = fmaf(a.r, b.i, fmaf( a.i, b.r, acc.i));
    return acc;
}

// Load/store a 2x2 complex matrix (8 floats, 32B aligned): m[i*2+j]
__device__ __forceinline__ void load_mat(const float* __restrict__ p, Cplx m[4]) {
    const float4* p4 = (const float4*)p;
    float4 v0 = p4[0];
    float4 v1 = p4[1];
    m[0].r = v0.x; m[0].i = v0.y;
    m[1].r = v0.z; m[1].i = v0.w;
    m[2].r = v1.x; m[2].i = v1.y;
    m[3].r = v1.z; m[3].i = v1.w;
}
__device__ __forceinline__ void store_mat(float* __restrict__ p, const Cplx m[4]) {
    float4* p4 = (float4*)p;
    p4[0] = make_float4(m[0].r, m[0].i, m[1].r, m[1].i);
    p4[1] = make_float4(m[2].r, m[2].i, m[3].r, m[3].i);
}

// out = a @ m   (2x2 complex matmul)
__device__ __forceinline__ void matmul(const Cplx a[4], const Cplx m[4], Cplx out[4]) {
    #pragma unroll
    for (int ik = 0; ik < 4; ++ik) {
        int i = ik >> 1, k = ik & 1;
        Cplx t = cmul(a[i * 2 + 0], m[0 * 2 + k]);
        out[ik] = cfma(a[i * 2 + 1], m[1 * 2 + k], t);
    }
}
// out = a @ m + x
__device__ __forceinline__ void matmul_add(const Cplx a[4], const Cplx m[4],
                                           const Cplx x[4], Cplx out[4]) {
    #pragma unroll
    for (int ik = 0; ik < 4; ++ik) {
        int i = ik >> 1, k = ik & 1;
        Cplx t = cfma(a[i * 2 + 0], m[0 * 2 + k], x[ik]);
        out[ik] = cfma(a[i * 2 + 1], m[1 * 2 + k], t);
    }
}

// Pass 1: per-segment composed transform (A_cum, X_cum) -> ws
// ws layout: [b][s][c][16 floats] = Ac(8) | Xc(8)
__global__ __launch_bounds__(256) void pscan_pass1(const float* __restrict__ A,
                                                   const float* __restrict__ X,
                                                   float* __restrict__ ws) {
    int bid = blockIdx.x;
    int cg = bid % CG;
    int s  = (bid / CG) % NSEG;
    int b  = bid / (CG * NSEG);
    int c  = cg * CBLK + threadIdx.x;

    long l0   = (long)s * SEGLEN;
    long base = (((long)b * LL + l0) * CC + c) * 8;
    const long step = (long)CC * 8;

    Cplx Ac[4], Xc[4];
    load_mat(A + base, Ac);
    load_mat(X + base, Xc);
    base += step;

    #pragma unroll 4
    for (int t = 1; t < SEGLEN; ++t, base += step) {
        Cplx a[4], x[4], nA[4], nX[4];
        load_mat(A + base, a);
        load_mat(X + base, x);
        matmul(a, Ac, nA);          // Ac = a @ Ac
        matmul_add(a, Xc, x, nX);   // Xc = a @ Xc + x
        #pragma unroll
        for (int j = 0; j < 4; ++j) { Ac[j] = nA[j]; Xc[j] = nX[j]; }
    }

    float* w = ws + (((long)b * NSEG + s) * CC + c) * 16;
    store_mat(w,     Ac);
    store_mat(w + 8, Xc);
}

// Pass 2: serial scan over the NSEG summaries per (b,c).
// Writes the carry Y entering segment s over the (consumed) Ac slot.
__global__ __launch_bounds__(256) void pscan_pass2(float* __restrict__ ws) {
    int t = blockIdx.x * blockDim.x + threadIdx.x;   // [0, BB*CC)
    int b = t / CC;
    int c = t % CC;

    Cplx Y[4];
    #pragma unroll
    for (int j = 0; j < 4; ++j) { Y[j].r = 0.f; Y[j].i = 0.f; }

    for (int s = 0; s < NSEG; ++s) {
        float* w = ws + (((long)b * NSEG + s) * CC + c) * 16;
        Cplx Ac[4], Xc[4];
        load_mat(w,     Ac);
        load_mat(w + 8, Xc);
        store_mat(w, Y);            // carry entering segment s (Ac consumed)
        Cplx nY[4];
        matmul_add(Ac, Y, Xc, nY);  // Y_end = Ac @ Y + Xc
        #pragma unroll
        for (int j = 0; j < 4; ++j) Y[j] = nY[j];
    }
}

// Pass 3: re-run recurrence per segment seeded with carry; write output.
__global__ __launch_bounds__(256) void pscan_pass3(const float* __restrict__ A,
                                                   const float* __restrict__ X,
                                                   const float* __restrict__ ws,
                                                   float* __restrict__ out) {
    int bid = blockIdx.x;
    int cg = bid % CG;
    int s  = (bid / CG) % NSEG;
    int b  = bid / (CG * NSEG);
    int c  = cg * CBLK + threadIdx.x;

    const float* w = ws + (((long)b * NSEG + s) * CC + c) * 16;
    Cplx Y[4];
    load_mat(w, Y);

    long l0   = (long)s * SEGLEN;
    long base = (((long)b * LL + l0) * CC + c) * 8;
    const long step = (long)CC * 8;

    #pragma unroll 4
    for (int t = 0; t < SEGLEN; ++t, base += step) {
        Cplx a[4], x[4], nY[4];
        load_mat(A + base, a);
        load_mat(X + base, x);
        matmul_add(a, Y, x, nY);    // Y = a @ Y + x
        #pragma unroll
        for (int j = 0; j < 4; ++j) Y[j] = nY[j];
        store_mat(out + base, Y);
    }
}

extern "C" void kernel_launch(void* const* d_in, const int* in_sizes, int n_in,
                              void* d_out, int out_size, void* d_ws, size_t ws_size,
                              hipStream_t stream) {
    const float* A = (const float*)d_in[0];
    const float* X = (const float*)d_in[1];
    float* out = (float*)d_out;
    float* ws  = (float*)d_ws;   // needs BB*NSEG*CC*16*4 = 16 MiB

    dim3 blk(256);
    pscan_pass1<<<BB * NSEG * CG, blk, 0, stream>>>(A, X, ws);
    pscan_pass2<<<(BB * CC) / 256, blk, 0, stream>>>(ws);
    pscan_pass3<<<BB * NSEG * CG, blk, 0, stream>>>(A, X, ws, out);
}